// Round 5
// baseline (198.173 us; speedup 1.0000x reference)
//
#include <hip/hip_runtime.h>
#include <hip/hip_cooperative_groups.h>

namespace cg = cooperative_groups;

#define E_N 65536
#define T_N 9

typedef __bf16 bf16x8 __attribute__((ext_vector_type(8)));
typedef float f32x4 __attribute__((ext_vector_type(4)));
typedef unsigned short ushort8 __attribute__((ext_vector_type(8)));
union U8 { ushort8 u; bf16x8 b; };
union BF2 { __bf16 h[2]; unsigned int u; };

// ---------------- ws layout (float offsets) ----------------
#define OFF_CB   0          // 9*256*256 ushort = 294912 floats (bf16 packed C)
#define OFF_ABC  294912     // 56*256 floats
#define OFF_D2   309248     // 9*256 floats
#define OFF_BH   311552     // 9*256 ints (per-block histograms)
#define OFF_CNT  313856     // 16 ints
#define OFF_IDX  313872     // 9*65536 ints
#define WS_NEED_BYTES ((size_t)(313872 + 589824) * 4)

__device__ __constant__ float SCALES_C[9][4] = {
  {1.f,    1e-6f, 1.f,  1.f},
  {1.f,    1e-6f, 1.f,  1.f},
  {1.f,    1.f,   1.f,  1.f},
  {1e3f,   1.f,   1.f,  1.f},
  {1e-12f, 1.f,   1.f,  1.f},
  {1e-9f,  1.f,   1.f,  1.f},
  {1.f,    1.f,   1.f,  1.f},
  {1e-3f,  1e-3f, 1.f,  1.f},
  {1.f,    1.f,   1e9f, 1.f},
};

__device__ inline unsigned short f2bf(float f) {
  unsigned int u = __float_as_uint(f);
  unsigned int r = (u + 0x7FFFu + ((u >> 16) & 1u)) >> 16;
  return (unsigned short)r;
}

// ---------------- shared-memory union (34 KB -> 4 blocks/CU) ----------------
struct GemmSM {
  unsigned short hb[64 * 256];  // 32 KB; bf16 h (swizzled), f32 rows in epilogue
  int eidx[64];
  float4 xs[64];
};
struct CSM {
  float w2s[8][256];            // 8 KB
  float partf[3 * 64 * 32];     // 24 KB k-quarter partials
};
struct ScatSM {
  int sph[9][4];
  int redw[9][4];
  int sbase[9];
};
union SM { GemmSM g; CSM c; ScatSM s; };

// ============ K1: per-block histogram ============
__global__ __launch_bounds__(256) void k_hist(const int* __restrict__ base_ids,
                                              int* __restrict__ bh) {
  __shared__ int ph[9][4];
  int b = blockIdx.x, tid = threadIdx.x;
  int e = (b << 8) + tid;
  int bt = base_ids[e];
  int w = tid >> 6, lane = tid & 63;
  #pragma unroll 1
  for (int t = 0; t < T_N; ++t) {
    unsigned long long m = __ballot(bt == t);
    if (lane == 0) ph[t][w] = __popcll(m);
  }
  __syncthreads();
  if (tid < T_N)
    bh[(tid << 8) + b] = ph[tid][0] + ph[tid][1] + ph[tid][2] + ph[tid][3];
}

// ============ K2: cooperative fused kernel ============
// phase: -1 = cooperative (P1 + grid.sync + P2); 1 = P1 only; 2 = P2 only.
__global__ __launch_bounds__(256, 4) void fused(
    int phase,
    const int* __restrict__ base_ids, const int* __restrict__ type_ids,
    const int* __restrict__ source_ids, const float* __restrict__ params,
    const float* __restrict__ te, const float* __restrict__ se,
    const float* __restrict__ W1, const float* __restrict__ b1,
    const float* __restrict__ W2, const float* __restrict__ b2,
    const float* __restrict__ Wf, const float* __restrict__ bfv,
    const int* __restrict__ bh,
    int* cnt, int* idxArr, unsigned short* Cb,
    float* ABc, float* D2b, float* out) {
  __shared__ SM sm;
  int tid = threadIdx.x;
  int nb = gridDim.x;
  int lane = tid & 63;
  int w = tid >> 6;

  // ---------------- P1: scatter | embed | C, grid-strided ----------------
  if (phase <= 1) {
    for (int it = blockIdx.x; it < 609; it += nb) {
      if (it < 256) {
        // ---- scatter chunk g with self-computed prefix from bh ----
        int g = it;
        int e = (g << 8) + tid;
        int bt = base_ids[e];
        int pk = e | (type_ids[e] << 16) | (source_ids[e] << 20);
        unsigned long long lanebit = 1ull << lane;

        #pragma unroll 1
        for (int t = 0; t < T_N; ++t) {
          unsigned long long m = __ballot(bt == t);
          if (lane == 0) sm.s.sph[t][w] = __popcll(m);
        }
        int v[9];
        #pragma unroll
        for (int t = 0; t < T_N; ++t) v[t] = (tid < g) ? bh[(t << 8) + tid] : 0;
        #pragma unroll
        for (int off = 32; off >= 1; off >>= 1) {
          #pragma unroll
          for (int t = 0; t < T_N; ++t) v[t] += __shfl_xor(v[t], off, 64);
        }
        if (lane == 0) {
          #pragma unroll
          for (int t = 0; t < T_N; ++t) sm.s.redw[t][w] = v[t];
        }
        __syncthreads();
        if (tid < T_N) {
          sm.s.sbase[tid] = sm.s.redw[tid][0] + sm.s.redw[tid][1] +
                            sm.s.redw[tid][2] + sm.s.redw[tid][3];
          int tot = sm.s.sph[tid][0] + sm.s.sph[tid][1] +
                    sm.s.sph[tid][2] + sm.s.sph[tid][3];
          if (g == 255) cnt[tid] = sm.s.sbase[tid] + tot;
          int o = 0;
          #pragma unroll
          for (int ww = 0; ww < 4; ++ww) {
            int tmp = sm.s.sph[tid][ww]; sm.s.sph[tid][ww] = o; o += tmp;
          }
        }
        __syncthreads();
        #pragma unroll 1
        for (int t = 0; t < T_N; ++t) {
          unsigned long long m = __ballot(bt == t);
          if (bt == t) {
            int pos = sm.s.sbase[t] + sm.s.sph[t][w] + __popcll(m & (lanebit - 1ull));
            idxArr[t * E_N + pos] = pk;
          }
        }
      } else if (it < 321) {
        // ---- embed/bias projections ----
        int bb = it - 256, d = tid;
        if (bb < 56) {
          int ty = bb >> 2, sr = bb & 3;
          const float* t0 = te + ty * 256;
          const float* s0 = se + sr * 256;
          float a0 = 0.f, a1 = 0.f, a2 = 0.f, a3 = 0.f;
          #pragma unroll 4
          for (int k = 0; k < 256; k += 4) {
            a0 = fmaf(t0[k + 0], Wf[((k + 0) << 8) + d], a0);
            a1 = fmaf(t0[k + 1], Wf[((k + 1) << 8) + d], a1);
            a2 = fmaf(t0[k + 2], Wf[((k + 2) << 8) + d], a2);
            a3 = fmaf(t0[k + 3], Wf[((k + 3) << 8) + d], a3);
          }
          #pragma unroll 4
          for (int k = 0; k < 256; k += 4) {
            a0 = fmaf(s0[k + 0], Wf[((256 + k + 0) << 8) + d], a0);
            a1 = fmaf(s0[k + 1], Wf[((256 + k + 1) << 8) + d], a1);
            a2 = fmaf(s0[k + 2], Wf[((256 + k + 2) << 8) + d], a2);
            a3 = fmaf(s0[k + 3], Wf[((256 + k + 3) << 8) + d], a3);
          }
          ABc[(bb << 8) + d] = (a0 + a1) + (a2 + a3);
        } else {
          int t = bb - 56;
          const float* bp = b2 + t * 256;
          float a0 = bfv[d], a1 = 0.f, a2 = 0.f, a3 = 0.f;
          #pragma unroll 4
          for (int k = 0; k < 256; k += 4) {
            a0 = fmaf(bp[k + 0], Wf[((512 + k + 0) << 8) + d], a0);
            a1 = fmaf(bp[k + 1], Wf[((512 + k + 1) << 8) + d], a1);
            a2 = fmaf(bp[k + 2], Wf[((512 + k + 2) << 8) + d], a2);
            a3 = fmaf(bp[k + 3], Wf[((512 + k + 3) << 8) + d], a3);
          }
          D2b[(t << 8) + d] = (a0 + a1) + (a2 + a3);
        }
      } else {
        // ---- C[t] = W2[t] @ Wf2, per-wave k-quarter + LDS reduce ----
        int ci = it - 321;
        int t = ci >> 5;
        int j0 = (ci & 31) << 3;
        for (int i = tid; i < 2048; i += 256)
          sm.c.w2s[i >> 8][i & 255] =
              W2[(size_t)t * 65536 + (size_t)(j0 + (i >> 8)) * 256 + (i & 255)];
        __syncthreads();

        int dg = lane << 2;
        int kbase = w << 6;
        f32x4 acc[8];
        #pragma unroll
        for (int j = 0; j < 8; ++j) acc[j] = (f32x4){0.f, 0.f, 0.f, 0.f};
        #pragma unroll 2
        for (int k0 = 0; k0 < 64; k0 += 4) {
          f32x4 a[8];
          #pragma unroll
          for (int j = 0; j < 8; ++j) a[j] = *(const f32x4*)&sm.c.w2s[j][kbase + k0];
          #pragma unroll
          for (int kk = 0; kk < 4; ++kk) {
            f32x4 wv = *(const f32x4*)&Wf[((512 + kbase + k0 + kk) << 8) + dg];
            #pragma unroll
            for (int j = 0; j < 8; ++j) {
              float aj = a[j][kk];
              acc[j].x = fmaf(aj, wv.x, acc[j].x);
              acc[j].y = fmaf(aj, wv.y, acc[j].y);
              acc[j].z = fmaf(aj, wv.z, acc[j].z);
              acc[j].w = fmaf(aj, wv.w, acc[j].w);
            }
          }
        }
        if (w > 0) {
          int fb = (((w - 1) << 6) + lane) << 5;
          #pragma unroll
          for (int j = 0; j < 8; ++j)
            *(f32x4*)&sm.c.partf[fb + ((j ^ (lane & 7)) << 2)] = acc[j];
        }
        __syncthreads();
        if (w == 0) {
          #pragma unroll
          for (int p = 0; p < 3; ++p) {
            int fb = ((p << 6) + lane) << 5;
            #pragma unroll
            for (int j = 0; j < 8; ++j)
              acc[j] += *(const f32x4*)&sm.c.partf[fb + ((j ^ (lane & 7)) << 2)];
          }
          unsigned short* CbT = Cb + (size_t)t * 65536;
          #pragma unroll
          for (int di = 0; di < 4; ++di) {
            ushort8 o;
            #pragma unroll
            for (int j = 0; j < 8; ++j) o[j] = f2bf(acc[j][di]);
            *(ushort8*)(CbT + ((size_t)((j0 >> 3) << 8) + dg + di) * 8) = o;
          }
        }
      }
      __syncthreads();
    }
  }

  if (phase < 0) {
    __threadfence();
    cg::this_grid().sync();
  }

  // ---------------- P2: grouped MFMA gemm, grid-strided over tiles ----------------
  if (phase < 0 || phase == 2) {
    int tcnt[9];
    #pragma unroll
    for (int i2 = 0; i2 < 9; ++i2) tcnt[i2] = cnt[i2];
    int tot = 0;
    #pragma unroll
    for (int i2 = 0; i2 < 9; ++i2) tot += (tcnt[i2] + 63) >> 6;

    for (int tile = blockIdx.x; tile < tot; tile += nb) {
      __syncthreads();
      int t = 0, m0 = 0, accb = 0;
      #pragma unroll
      for (int tt = 0; tt < T_N; ++tt) {
        int nbk = (tcnt[tt] + 63) >> 6;
        if (tile >= accb && tile < accb + nbk) { t = tt; m0 = (tile - accb) << 6; }
        accb += nbk;
      }
      int n = tcnt[t];

      if (tid < 64) {
        int m = m0 + tid;
        int mc = (m < n) ? m : (n - 1);
        int pk = idxArr[(size_t)t * E_N + mc];
        sm.g.eidx[tid] = pk;
        int e = pk & 0xFFFF;
        float4 pr = *(const float4*)(params + (size_t)e * 4);
        float4 x;
        x.x = pr.x / SCALES_C[t][0];
        x.y = pr.y / SCALES_C[t][1];
        x.z = pr.z / SCALES_C[t][2];
        x.w = pr.w / SCALES_C[t][3];
        sm.g.xs[tid] = x;
      }
      __syncthreads();

      // phase B: h = relu(x@W1+b1) -> bf16 packed pairs, XOR-swizzled LDS
      {
        int dp = tid & 127, mh = tid >> 7;
        int d0 = dp << 1;
        const float* W1t = W1 + t * 1024;
        float2 wq0 = *(const float2*)&W1t[d0];
        float2 wq1 = *(const float2*)&W1t[256 + d0];
        float2 wq2 = *(const float2*)&W1t[512 + d0];
        float2 wq3 = *(const float2*)&W1t[768 + d0];
        float2 bq  = *(const float2*)&b1[t * 256 + d0];
        int mb = mh << 5;
        #pragma unroll 4
        for (int i = 0; i < 32; ++i) {
          int m = mb + i;
          float4 x = sm.g.xs[m];
          float h0 = fmaf(x.x, wq0.x, fmaf(x.y, wq1.x, fmaf(x.z, wq2.x, fmaf(x.w, wq3.x, bq.x))));
          float h1 = fmaf(x.x, wq0.y, fmaf(x.y, wq1.y, fmaf(x.z, wq2.y, fmaf(x.w, wq3.y, bq.y))));
          BF2 pk2;
          pk2.h[0] = (__bf16)fmaxf(h0, 0.f);
          pk2.h[1] = (__bf16)fmaxf(h1, 0.f);
          int off = (m << 9) + ((d0 << 1) ^ ((m & 7) << 4));
          *(unsigned int*)((char*)sm.g.hb + off) = pk2.u;
        }
      }
      __syncthreads();

      int l15 = lane & 15;
      int l4 = lane >> 4;
      f32x4 acc[4][4];
      #pragma unroll
      for (int i = 0; i < 4; ++i)
        #pragma unroll
        for (int j = 0; j < 4; ++j) acc[i][j] = (f32x4){0.f, 0.f, 0.f, 0.f};

      const unsigned short* CbT = Cb + (size_t)t * 65536;
      #pragma unroll 1
      for (int s = 0; s < 8; ++s) {
        bf16x8 bfr[4];
        #pragma unroll
        for (int nn = 0; nn < 4; ++nn) {
          int koct = (s << 2) + l4;
          int d = (w << 6) + (nn << 4) + l15;
          U8 u;
          u.u = *(const ushort8*)(CbT + (size_t)((koct << 8) + d) * 8);
          bfr[nn] = u.b;
        }
        __builtin_amdgcn_s_setprio(1);
        #pragma unroll
        for (int mt = 0; mt < 4; ++mt) {
          int row = (mt << 4) + l15;
          int byte = (row << 9) + ((((s << 6) + (l4 << 4))) ^ ((row & 7) << 4));
          U8 a;
          a.u = *(const ushort8*)((const char*)sm.g.hb + byte);
          #pragma unroll
          for (int nn = 0; nn < 4; ++nn)
            acc[mt][nn] = __builtin_amdgcn_mfma_f32_16x16x32_bf16(a.b, bfr[nn], acc[mt][nn], 0, 0, 0);
        }
        __builtin_amdgcn_s_setprio(0);
      }

      // epilogue: transpose through LDS, vectorized bias add + store
      float* fb = (float*)sm.g.hb;
      const float* d2p = D2b + (t << 8);
      #pragma unroll
      for (int p = 0; p < 2; ++p) {
        __syncthreads();
        #pragma unroll
        for (int mh2 = 0; mh2 < 2; ++mh2) {
          int mt = (p << 1) + mh2;
          int lrb = (mh2 << 4) + (l4 << 2);
          #pragma unroll
          for (int nn = 0; nn < 4; ++nn) {
            int col = (w << 6) + (nn << 4) + l15;
            #pragma unroll
            for (int r = 0; r < 4; ++r) {
              int lr = lrb + r;
              fb[lr * 256 + (col ^ ((lr & 7) << 2))] = acc[mt][nn][r];
            }
          }
        }
        __syncthreads();
        int lr = tid >> 3;
        int c8 = tid & 7;
        int row_g = (p << 5) + lr;
        if (m0 + row_g < n) {
          int pk = sm.g.eidx[row_g];
          int e = pk & 0xFFFF;
          int ty = (pk >> 16) & 15;
          int sr = (pk >> 20) & 3;
          const float* abp = ABc + (size_t)(((ty << 2) + sr) << 8);
          float* op = out + (size_t)e * 256;
          int sw = (lr & 7) << 2;
          #pragma unroll
          for (int vv2 = 0; vv2 < 8; ++vv2) {
            int col = (c8 << 2) + (vv2 << 5);
            f32x4 vvv = *(const f32x4*)&fb[lr * 256 + (col ^ sw)];
            f32x4 ab = *(const f32x4*)&abp[col];
            f32x4 d2 = *(const f32x4*)&d2p[col];
            f32x4 rr;
            rr.x = fmaxf(vvv.x + ab.x + d2.x, 0.f);
            rr.y = fmaxf(vvv.y + ab.y + d2.y, 0.f);
            rr.z = fmaxf(vvv.z + ab.z + d2.z, 0.f);
            rr.w = fmaxf(vvv.w + ab.w + d2.w, 0.f);
            *(f32x4*)&op[col] = rr;
          }
        }
      }
    }
  }
}

extern "C" void kernel_launch(void* const* d_in, const int* in_sizes, int n_in,
                              void* d_out, int out_size, void* d_ws, size_t ws_size,
                              hipStream_t stream) {
  const int*   type_ids   = (const int*)  d_in[0];
  const int*   source_ids = (const int*)  d_in[1];
  const int*   base_ids   = (const int*)  d_in[2];
  const float* params     = (const float*)d_in[3];
  const float* te         = (const float*)d_in[4];
  const float* se         = (const float*)d_in[5];
  const float* W1         = (const float*)d_in[6];
  const float* b1         = (const float*)d_in[7];
  const float* W2         = (const float*)d_in[8];
  const float* b2         = (const float*)d_in[9];
  const float* Wf         = (const float*)d_in[10];
  const float* bfv        = (const float*)d_in[11];
  float* out = (float*)d_out;

  if (ws_size < WS_NEED_BYTES) return;

  float* wsf = (float*)d_ws;
  unsigned short* Cb = (unsigned short*)(wsf + OFF_CB);
  float* ABc = wsf + OFF_ABC;
  float* D2b = wsf + OFF_D2;
  int*   bh  = (int*)(wsf + OFF_BH);
  int*   cnt = (int*)(wsf + OFF_CNT);
  int*   idx = (int*)(wsf + OFF_IDX);

  k_hist<<<256, 256, 0, stream>>>(base_ids, bh);

  // cooperative path: occupancy-derived grid (expect 4 blocks/CU * 256 CU = 1024)
  int maxb = 0;
  hipError_t oe = hipOccupancyMaxActiveBlocksPerMultiprocessor(
      &maxb, (const void*)fused, 256, 0);
  int grid = (oe == hipSuccess && maxb > 0) ? maxb * 256 : 0;
  if (grid > 1024) grid = 1024;
  bool coop = (grid >= 256);

  if (coop) {
    int ph = -1;
    void* args[] = {(void*)&ph,
                    (void*)&base_ids, (void*)&type_ids, (void*)&source_ids,
                    (void*)&params,   (void*)&te,       (void*)&se,
                    (void*)&W1,       (void*)&b1,       (void*)&W2,
                    (void*)&b2,       (void*)&Wf,       (void*)&bfv,
                    (void*)&bh,       (void*)&cnt,      (void*)&idx,
                    (void*)&Cb,       (void*)&ABc,      (void*)&D2b,
                    (void*)&out};
    hipError_t le = hipLaunchCooperativeKernel((const void*)fused, dim3(grid),
                                               dim3(256), args, 0, stream);
    if (le != hipSuccess) coop = false;
  }
  if (!coop) {
    fused<<<609, 256, 0, stream>>>(1, base_ids, type_ids, source_ids, params,
                                   te, se, W1, b1, W2, b2, Wf, bfv, bh, cnt,
                                   idx, Cb, ABc, D2b, out);
    fused<<<1033, 256, 0, stream>>>(2, base_ids, type_ids, source_ids, params,
                                    te, se, W1, b1, W2, b2, Wf, bfv, bh, cnt,
                                    idx, Cb, ABc, D2b, out);
  }
}

// Round 6
// 58.972 us; speedup vs baseline: 3.3604x; 3.3604x over previous
//
#include <hip/hip_runtime.h>

#define E_N 65536
#define T_N 9

typedef __bf16 bf16x8 __attribute__((ext_vector_type(8)));
typedef float f32x4 __attribute__((ext_vector_type(4)));
typedef unsigned short ushort8 __attribute__((ext_vector_type(8)));
union U8 { ushort8 u; bf16x8 b; };

// ---------------- ws layout (float offsets) ----------------
#define OFF_CB   0          // 9*256*256 ushort = 294912 floats (bf16 packed C)
#define OFF_ABC  294912     // 56*256 floats
#define OFF_D2   309248     // 9*256 floats
#define OFF_CNT  311552     // 16 ints
#define OFF_IDX  311568     // 9*65536 ints
#define WS_NEED_BYTES ((size_t)(311568 + 589824) * 4)

__device__ __constant__ float SCALES_C[9][4] = {
  {1.f,    1e-6f, 1.f,  1.f},
  {1.f,    1e-6f, 1.f,  1.f},
  {1.f,    1.f,   1.f,  1.f},
  {1e3f,   1.f,   1.f,  1.f},
  {1e-12f, 1.f,   1.f,  1.f},
  {1e-9f,  1.f,   1.f,  1.f},
  {1.f,    1.f,   1.f,  1.f},
  {1e-3f,  1e-3f, 1.f,  1.f},
  {1.f,    1.f,   1e9f, 1.f},
};

__device__ inline unsigned short f2bf(float f) {
  unsigned int u = __float_as_uint(f);
  unsigned int r = (u + 0x7FFFu + ((u >> 16) & 1u)) >> 16;
  return (unsigned short)r;
}

// ============ K1: fused independent prep ============
// blocks [0,256): scatter (block-aggregated atomics)
// blocks [256,321): embed/bias projections (k-split across waves + LDS reduce)
// blocks [321,609): C[t] = W2[t]@Wf2 (per-wave k-quarter, conflict-free partials)
struct ScatSM { int sph[9][4]; int sbase[9]; };
struct EmbSM  { float partf[4 * 64 * 4]; };           // [wave][lane] f32x4, 4 KB
struct CSM    { float w2s[8][256]; float partf[3 * 8 * 64 * 4]; };  // 8 + 24 KB
union PrepSM  { ScatSM s; EmbSM e; CSM c; };

__global__ __launch_bounds__(256) void k_prep(
    const int* __restrict__ base_ids, const int* __restrict__ type_ids,
    const int* __restrict__ source_ids,
    const float* __restrict__ te, const float* __restrict__ se,
    const float* __restrict__ b2, const float* __restrict__ Wf,
    const float* __restrict__ bfv, const float* __restrict__ W2,
    int* __restrict__ cnt, int* __restrict__ idxArr,
    unsigned short* __restrict__ Cb,
    float* __restrict__ ABc, float* __restrict__ D2b) {
  __shared__ PrepSM sm;
  int b = blockIdx.x;
  int tid = threadIdx.x;
  int lane = tid & 63;
  int w = tid >> 6;

  if (b < 256) {
    // ---- scatter: per-block LDS aggregation, one atomic per (block,type) ----
    int e = (b << 8) + tid;
    int bt = base_ids[e];
    int pk = e | (type_ids[e] << 16) | (source_ids[e] << 20);
    unsigned long long lanebit = 1ull << lane;

    #pragma unroll 1
    for (int t = 0; t < T_N; ++t) {
      unsigned long long m = __ballot(bt == t);
      if (lane == 0) sm.s.sph[t][w] = __popcll(m);
    }
    __syncthreads();
    if (tid < T_N) {
      int c0 = sm.s.sph[tid][0], c1 = sm.s.sph[tid][1];
      int c2 = sm.s.sph[tid][2], c3 = sm.s.sph[tid][3];
      int tot = c0 + c1 + c2 + c3;
      int base = (tot > 0) ? atomicAdd(&cnt[tid], tot) : 0;
      sm.s.sbase[tid] = base;
      sm.s.sph[tid][0] = 0;
      sm.s.sph[tid][1] = c0;
      sm.s.sph[tid][2] = c0 + c1;
      sm.s.sph[tid][3] = c0 + c1 + c2;
    }
    __syncthreads();
    #pragma unroll 1
    for (int t = 0; t < T_N; ++t) {
      unsigned long long m = __ballot(bt == t);
      if (bt == t) {
        int pos = sm.s.sbase[t] + sm.s.sph[t][w] + __popcll(m & (lanebit - 1ull));
        idxArr[t * E_N + pos] = pk;
      }
    }
  } else if (b < 321) {
    // ---- embed: each wave takes a k-chunk, lanes take 4 d-columns ----
    int bb = b - 256;
    int dg = lane << 2;
    f32x4 acc0 = {0.f, 0.f, 0.f, 0.f}, acc1 = {0.f, 0.f, 0.f, 0.f};
    if (bb < 56) {
      // ABc[ty][sr] = te[ty]@Wf[0:256] + se[sr]@Wf[256:512]; 512 k over 4 waves
      int ty = bb >> 2, sr = bb & 3;
      const float* src = (w < 2) ? (te + ty * 256) : (se + sr * 256 - 256);
      int kbase = w << 7;
      #pragma unroll 8
      for (int k = kbase; k < kbase + 128; k += 2) {
        f32x4 wv0 = *(const f32x4*)&Wf[((k + 0) << 8) + dg];
        f32x4 wv1 = *(const f32x4*)&Wf[((k + 1) << 8) + dg];
        float e0 = src[k], e1 = src[k + 1];
        acc0.x = fmaf(e0, wv0.x, acc0.x); acc0.y = fmaf(e0, wv0.y, acc0.y);
        acc0.z = fmaf(e0, wv0.z, acc0.z); acc0.w = fmaf(e0, wv0.w, acc0.w);
        acc1.x = fmaf(e1, wv1.x, acc1.x); acc1.y = fmaf(e1, wv1.y, acc1.y);
        acc1.z = fmaf(e1, wv1.z, acc1.z); acc1.w = fmaf(e1, wv1.w, acc1.w);
      }
    } else {
      // D2b[t] = b2[t]@Wf[512:768] + bf; 256 k over 4 waves
      int t = bb - 56;
      const float* bp = b2 + t * 256;
      int kbase = w << 6;
      #pragma unroll 8
      for (int k = kbase; k < kbase + 64; k += 2) {
        f32x4 wv0 = *(const f32x4*)&Wf[((512 + k + 0) << 8) + dg];
        f32x4 wv1 = *(const f32x4*)&Wf[((512 + k + 1) << 8) + dg];
        float e0 = bp[k], e1 = bp[k + 1];
        acc0.x = fmaf(e0, wv0.x, acc0.x); acc0.y = fmaf(e0, wv0.y, acc0.y);
        acc0.z = fmaf(e0, wv0.z, acc0.z); acc0.w = fmaf(e0, wv0.w, acc0.w);
        acc1.x = fmaf(e1, wv1.x, acc1.x); acc1.y = fmaf(e1, wv1.y, acc1.y);
        acc1.z = fmaf(e1, wv1.z, acc1.z); acc1.w = fmaf(e1, wv1.w, acc1.w);
      }
    }
    acc0 += acc1;
    // lane-contiguous partials: [w*64+lane] f32x4 -> banks 4l..4l+3, conflict-free
    *(f32x4*)&sm.e.partf[((w << 6) + lane) << 2] = acc0;
    __syncthreads();
    if (w == 0) {
      acc0 += *(const f32x4*)&sm.e.partf[((1 << 6) + lane) << 2];
      acc0 += *(const f32x4*)&sm.e.partf[((2 << 6) + lane) << 2];
      acc0 += *(const f32x4*)&sm.e.partf[((3 << 6) + lane) << 2];
      if (bb < 56) {
        *(f32x4*)&ABc[(bb << 8) + dg] = acc0;
      } else {
        f32x4 bv = *(const f32x4*)&bfv[dg];
        *(f32x4*)&D2b[((bb - 56) << 8) + dg] = acc0 + bv;
      }
    }
  } else {
    // ---- C[t] = W2[t] @ Wf2: per-wave k-quarter + LDS reduce (transposed partf) ----
    int ci = b - 321;
    int t = ci >> 5;
    int j0 = (ci & 31) << 3;
    for (int i = tid; i < 2048; i += 256)
      sm.c.w2s[i >> 8][i & 255] =
          W2[(size_t)t * 65536 + (size_t)(j0 + (i >> 8)) * 256 + (i & 255)];
    __syncthreads();

    int dg = lane << 2;
    int kbase = w << 6;
    f32x4 acc[8];
    #pragma unroll
    for (int j = 0; j < 8; ++j) acc[j] = (f32x4){0.f, 0.f, 0.f, 0.f};
    #pragma unroll 2
    for (int k0 = 0; k0 < 64; k0 += 4) {
      f32x4 a[8];
      #pragma unroll
      for (int j = 0; j < 8; ++j) a[j] = *(const f32x4*)&sm.c.w2s[j][kbase + k0];
      #pragma unroll
      for (int kk = 0; kk < 4; ++kk) {
        f32x4 wv = *(const f32x4*)&Wf[((512 + kbase + k0 + kk) << 8) + dg];
        #pragma unroll
        for (int j = 0; j < 8; ++j) {
          float aj = a[j][kk];
          acc[j].x = fmaf(aj, wv.x, acc[j].x);
          acc[j].y = fmaf(aj, wv.y, acc[j].y);
          acc[j].z = fmaf(aj, wv.z, acc[j].z);
          acc[j].w = fmaf(aj, wv.w, acc[j].w);
        }
      }
    }
    // waves 1..3 stash partials lane-contiguously: [ (w-1)*8+j ][lane] f32x4
    if (w > 0) {
      #pragma unroll
      for (int j = 0; j < 8; ++j)
        *(f32x4*)&sm.c.partf[(((((w - 1) << 3) + j) << 6) + lane) << 2] = acc[j];
    }
    __syncthreads();
    if (w == 0) {
      #pragma unroll
      for (int p = 0; p < 3; ++p)
        #pragma unroll
        for (int j = 0; j < 8; ++j)
          acc[j] += *(const f32x4*)&sm.c.partf[((((p << 3) + j) << 6) + lane) << 2];
      unsigned short* CbT = Cb + (size_t)t * 65536;
      #pragma unroll
      for (int di = 0; di < 4; ++di) {
        ushort8 o;
        #pragma unroll
        for (int j = 0; j < 8; ++j) o[j] = f2bf(acc[j][di]);
        *(ushort8*)(CbT + ((size_t)((j0 >> 3) << 8) + dg + di) * 8) = o;
      }
    }
  }
}

// ============ K2: grouped GEMM via MFMA (round-4 validated kernel) ============
__global__ __launch_bounds__(256, 4) void edge_gemm(
    const int* __restrict__ cnt, const int* __restrict__ idxArr,
    const float* __restrict__ params,
    const float* __restrict__ W1, const float* __restrict__ b1,
    const unsigned short* __restrict__ Cb, const float* __restrict__ ABc,
    const float* __restrict__ D2b, float* __restrict__ out) {
  int b = blockIdx.x;
  int t = -1, m0 = 0, n = 0;
  {
    int acc = 0;
    #pragma unroll
    for (int tt = 0; tt < T_N; ++tt) {
      int c = cnt[tt];
      int nb = (c + 63) >> 6;
      if (t < 0 && b < acc + nb) { t = tt; m0 = (b - acc) << 6; n = c; }
      acc += nb;
    }
  }
  if (t < 0) return;

  __shared__ unsigned short hb[64 * 256];  // 32 KB; bf16 h (swizzled) then f32 rows
  __shared__ int eidx[64];                 // packed e|ty<<16|sr<<20
  __shared__ float4 xs[64];

  int tid = threadIdx.x;
  if (tid < 64) {
    int m = m0 + tid;
    int mc = (m < n) ? m : (n - 1);
    int pk = idxArr[(size_t)t * E_N + mc];
    eidx[tid] = pk;
    int e = pk & 0xFFFF;
    float4 pr = *(const float4*)(params + (size_t)e * 4);
    float4 x;
    x.x = pr.x / SCALES_C[t][0];
    x.y = pr.y / SCALES_C[t][1];
    x.z = pr.z / SCALES_C[t][2];
    x.w = pr.w / SCALES_C[t][3];
    xs[tid] = x;
  }
  __syncthreads();

  {
    int d = tid;
    const float* W1t = W1 + t * 1024;
    float w0 = W1t[d], w1 = W1t[256 + d], w2 = W1t[512 + d], w3 = W1t[768 + d];
    float b1d = b1[t * 256 + d];
    int dbyte = d << 1;
    #pragma unroll 4
    for (int m = 0; m < 64; ++m) {
      float4 x = xs[m];
      float h = fmaf(x.x, w0, fmaf(x.y, w1, fmaf(x.z, w2, fmaf(x.w, w3, b1d))));
      h = fmaxf(h, 0.f);
      int off = (m << 9) + (dbyte ^ ((m & 7) << 4));
      hb[off >> 1] = f2bf(h);
    }
  }
  __syncthreads();

  int lane = tid & 63;
  int w = tid >> 6;
  int l15 = lane & 15;
  int l4 = lane >> 4;

  f32x4 acc[4][4];
  #pragma unroll
  for (int i = 0; i < 4; ++i)
    #pragma unroll
    for (int j = 0; j < 4; ++j) acc[i][j] = (f32x4){0.f, 0.f, 0.f, 0.f};

  const unsigned short* CbT = Cb + (size_t)t * 65536;

  #pragma unroll 1
  for (int s = 0; s < 8; ++s) {
    bf16x8 bfr[4];
    #pragma unroll
    for (int nn = 0; nn < 4; ++nn) {
      int koct = (s << 2) + l4;
      int d = (w << 6) + (nn << 4) + l15;
      U8 u;
      u.u = *(const ushort8*)(CbT + (size_t)((koct << 8) + d) * 8);
      bfr[nn] = u.b;
    }
    __builtin_amdgcn_s_setprio(1);
    #pragma unroll
    for (int mt = 0; mt < 4; ++mt) {
      int row = (mt << 4) + l15;
      int byte = (row << 9) + ((((s << 6) + (l4 << 4))) ^ ((row & 7) << 4));
      U8 a;
      a.u = *(const ushort8*)((const char*)hb + byte);
      #pragma unroll
      for (int nn = 0; nn < 4; ++nn)
        acc[mt][nn] = __builtin_amdgcn_mfma_f32_16x16x32_bf16(a.b, bfr[nn], acc[mt][nn], 0, 0, 0);
    }
    __builtin_amdgcn_s_setprio(0);
  }

  // epilogue: transpose through LDS (hb dead), vectorized bias add + store
  float* fb = (float*)hb;
  const float* d2p = D2b + (t << 8);
  #pragma unroll
  for (int p = 0; p < 2; ++p) {
    __syncthreads();
    #pragma unroll
    for (int mh = 0; mh < 2; ++mh) {
      int mt = (p << 1) + mh;
      int lrb = (mh << 4) + (l4 << 2);
      #pragma unroll
      for (int nn = 0; nn < 4; ++nn) {
        int col = (w << 6) + (nn << 4) + l15;
        #pragma unroll
        for (int r = 0; r < 4; ++r) {
          int lr = lrb + r;
          fb[lr * 256 + (col ^ ((lr & 7) << 2))] = acc[mt][nn][r];
        }
      }
    }
    __syncthreads();
    int lr = tid >> 3;
    int c8 = tid & 7;
    int row_g = (p << 5) + lr;
    if (m0 + row_g < n) {
      int pk = eidx[row_g];
      int e = pk & 0xFFFF;
      int ty = (pk >> 16) & 15;
      int sr = (pk >> 20) & 3;
      const float* abp = ABc + (size_t)(((ty << 2) + sr) << 8);
      float* op = out + (size_t)e * 256;
      int sw = (lr & 7) << 2;
      #pragma unroll
      for (int v = 0; v < 8; ++v) {
        int col = (c8 << 2) + (v << 5);
        f32x4 vv = *(const f32x4*)&fb[lr * 256 + (col ^ sw)];
        f32x4 ab = *(const f32x4*)&abp[col];
        f32x4 d2 = *(const f32x4*)&d2p[col];
        f32x4 rr;
        rr.x = fmaxf(vv.x + ab.x + d2.x, 0.f);
        rr.y = fmaxf(vv.y + ab.y + d2.y, 0.f);
        rr.z = fmaxf(vv.z + ab.z + d2.z, 0.f);
        rr.w = fmaxf(vv.w + ab.w + d2.w, 0.f);
        *(f32x4*)&op[col] = rr;
      }
    }
  }
}

extern "C" void kernel_launch(void* const* d_in, const int* in_sizes, int n_in,
                              void* d_out, int out_size, void* d_ws, size_t ws_size,
                              hipStream_t stream) {
  const int*   type_ids   = (const int*)  d_in[0];
  const int*   source_ids = (const int*)  d_in[1];
  const int*   base_ids   = (const int*)  d_in[2];
  const float* params     = (const float*)d_in[3];
  const float* te         = (const float*)d_in[4];
  const float* se         = (const float*)d_in[5];
  const float* W1         = (const float*)d_in[6];
  const float* b1         = (const float*)d_in[7];
  const float* W2         = (const float*)d_in[8];
  const float* b2         = (const float*)d_in[9];
  const float* Wf         = (const float*)d_in[10];
  const float* bfv        = (const float*)d_in[11];
  float* out = (float*)d_out;

  if (ws_size < WS_NEED_BYTES) return;

  float* wsf = (float*)d_ws;
  unsigned short* Cb = (unsigned short*)(wsf + OFF_CB);
  float* ABc = wsf + OFF_ABC;
  float* D2b = wsf + OFF_D2;
  int*   cnt = (int*)(wsf + OFF_CNT);
  int*   idx = (int*)(wsf + OFF_IDX);

  hipMemsetAsync(cnt, 0, 16 * sizeof(int), stream);
  k_prep<<<609, 256, 0, stream>>>(base_ids, type_ids, source_ids, te, se, b2,
                                  Wf, bfv, W2, cnt, idx, Cb, ABc, D2b);
  edge_gemm<<<1033, 256, 0, stream>>>(cnt, idx, params, W1, b1, Cb, ABc, D2b, out);
}